// Round 4
// baseline (219.223 us; speedup 1.0000x reference)
//
#include <hip/hip_runtime.h>
#include <stdint.h>

// ---------------------------------------------------------------------------
// Fused RBF histogram:  hist[o,i] = sum_n exp(-||x_n - c_o||^2 / 2) * x[n,i]
// N=524288, IN=64, OUT=128.  fp32 in/out.
//
// R4 = R3 with the compile fix (pkbf via RNE bit-trick; __hip_bfloat162 is
// not trivially copyable so __builtin_bit_cast rejected it).
// R3 changes vs R2 (~69us kernel, 3 blocks/CU, LDS-capped):
//  - stage B fused into stage A per nt-PAIR via wave-private sPw[32][40]
//    (10 KB total, was 18.4 KB shared sP) -> "P ready" barrier DELETED
//    (sP was always same-wave produce/consume; lgkmcnt suffices).
//  - LDS 46.6 -> 37.3 KB -> 4 blocks/CU (LDS was the occupancy cap).
//  - grid 1024 = 4 blocks/CU, 8 iters/block exactly; launch_bounds(256,4).
//  - scale x,c by sqrt(log2e) and pre-negate/halve x2,c2 so the MFMA
//    accumulator IS the exp2 argument.
// ---------------------------------------------------------------------------

typedef __bf16 bf16x8 __attribute__((ext_vector_type(8)));
typedef unsigned short ushortx8 __attribute__((ext_vector_type(8)));
typedef float floatx4 __attribute__((ext_vector_type(4)));

#define GRIDN 1024     // 4 blocks/CU x 256 CUs
#define NITER 8        // 8192 tiles / 1024 blocks
#define SCL 1.2011224087864498f   // sqrt(log2(e)); (x*SCL).(c*SCL) = log2e * x.c

#if __has_builtin(__builtin_amdgcn_exp2f)
#define EXP2F(x) __builtin_amdgcn_exp2f(x)
#else
#define EXP2F(x) exp2f(x)
#endif

// round-to-nearest-even fp32 -> bf16 (bit trick; no NaN inputs here)
static __device__ __forceinline__ unsigned int bfbits(float f) {
  unsigned int u = __float_as_uint(f);
  return u + 0x7fffu + ((u >> 16) & 1u);   // rounded value in high 16 bits
}
// pack two fp32 -> bf16x2 (RNE), a in low half
static __device__ __forceinline__ unsigned int pkbf(float a, float b) {
  return (bfbits(a) >> 16) | (bfbits(b) & 0xffff0000u);
}

static __device__ __forceinline__ floatx4 mfma_bf16(ushortx8 a, ushortx8 b, floatx4 c) {
  return __builtin_amdgcn_mfma_f32_16x16x32_bf16(
      __builtin_bit_cast(bf16x8, a), __builtin_bit_cast(bf16x8, b), c, 0, 0, 0);
}

// x-tile LDS row stride 72 shorts = 144 B: 16B-aligned rows, bank step 36%32=4
// -> b128 frag reads are <=2-way conflicted per 16-lane beat (free, m136).
// sPw row stride 40 shorts = 80 B: 16B-aligned, bank step 20 -> 2-way over 16 rows.
#define LSTR 72
#define PSTR 40

__global__ __launch_bounds__(256, 4) void rbf_hist_kernel(
    const float* __restrict__ x, const float* __restrict__ c,
    float* __restrict__ out, float* __restrict__ ws, int use_ws) {
  __shared__ unsigned short sXhi[64][LSTR];   // x*SCL tile, bf16 hi  [n][i]
  __shared__ unsigned short sXlo[64][LSTR];   // x*SCL tile, bf16 lo  [n][i]
  __shared__ unsigned short sXT [64][LSTR];   // x (unscaled) bf16, transposed [i][n]
  __shared__ unsigned short sPw [4][32][PSTR];// per-wave rbf pair-tile [o'][n' 0..31]
  __shared__ float          sX2 [64];         // -0.5 * ||x_n*SCL||^2 (fp32 exact)

  const int t    = threadIdx.x;
  const int lane = t & 63;
  const int w    = t >> 6;      // wave 0..3; owns o-tiles {2w, 2w+1}
  const int l15  = lane & 15;
  const int quad = lane >> 4;

  // ---- one-time: scaled c fragments (hi/lo) for this wave's 2 o-tiles ----
  // B-frag for stage A: B[k=i][col=o]: lane reads c[ot*16+l15][32s+quad*8 ..+7]
  uint4 chi[2][2], clo[2][2];   // packed bf16 pairs, j ascending
  float m2c[2];                 // -0.5 * ||c_o*SCL||^2
#pragma unroll
  for (int oo = 0; oo < 2; ++oo) {
    const int ot = 2 * w + oo;
    float sq = 0.f;
#pragma unroll
    for (int s = 0; s < 2; ++s) {
      const float* p = c + (ot * 16 + l15) * 64 + s * 32 + quad * 8;
      float4 va = *(const float4*)(p);
      float4 vb = *(const float4*)(p + 4);
      float f[8] = {va.x, va.y, va.z, va.w, vb.x, vb.y, vb.z, vb.w};
      unsigned int h[4], l[4];
#pragma unroll
      for (int jp = 0; jp < 4; ++jp) {
        float a = f[2 * jp] * SCL, b = f[2 * jp + 1] * SCL;
        sq = fmaf(a, a, sq);
        sq = fmaf(b, b, sq);
        unsigned int hp = pkbf(a, b);
        float la = a - __uint_as_float(hp << 16);
        float lb = b - __uint_as_float(hp & 0xffff0000u);
        h[jp] = hp;
        l[jp] = pkbf(la, lb);
      }
      chi[oo][s] = uint4{h[0], h[1], h[2], h[3]};
      clo[oo][s] = uint4{l[0], l[1], l[2], l[3]};
    }
    sq += __shfl_xor(sq, 16);
    sq += __shfl_xor(sq, 32);
    m2c[oo] = -0.5f * sq;
  }

  // persistent histogram accumulators: wave w owns o-tiles {2w,2w+1} x 4 i-tiles
  floatx4 hacc[2][4];
#pragma unroll
  for (int a = 0; a < 2; ++a)
#pragma unroll
    for (int b = 0; b < 4; ++b) {
      floatx4 z = {0.f, 0.f, 0.f, 0.f};
      hacc[a][b] = z;
    }

  // register prefetch of first x tile: thread t -> row r=t>>2, cols q*4+g*16
  const int r = t >> 2, q = t & 3;
  float4 v[4];
  {
    const size_t row0 = (size_t)(blockIdx.x * 64 + r) * 64;
#pragma unroll
    for (int g = 0; g < 4; ++g)
      v[g] = *(const float4*)(x + row0 + q * 4 + g * 16);
  }

  for (int it = 0; it < NITER; ++it) {
    __syncthreads();  // prev iteration's reads of sX* done -> safe to overwrite

    // ---- staging: regs -> LDS (scaled hi/lo, unscaled transposed, -x2/2) ----
    {
      float sq = 0.f;
#pragma unroll
      for (int g = 0; g < 4; ++g) {
        const int col = q * 4 + g * 16;
        float f0 = v[g].x, f1 = v[g].y, f2 = v[g].z, f3 = v[g].w;
        // unscaled bf16 for the histogram GEMM (stage B)
        unsigned int u01 = pkbf(f0, f1), u23 = pkbf(f2, f3);
        sXT[col + 0][r] = (unsigned short)(u01 & 0xffffu);
        sXT[col + 1][r] = (unsigned short)(u01 >> 16);
        sXT[col + 2][r] = (unsigned short)(u23 & 0xffffu);
        sXT[col + 3][r] = (unsigned short)(u23 >> 16);
        // scaled hi/lo split for the distance GEMM
        float s0 = f0 * SCL, s1 = f1 * SCL, s2 = f2 * SCL, s3 = f3 * SCL;
        sq = fmaf(s0, s0, sq); sq = fmaf(s1, s1, sq);
        sq = fmaf(s2, s2, sq); sq = fmaf(s3, s3, sq);
        unsigned int h01 = pkbf(s0, s1), h23 = pkbf(s2, s3);
        float l0 = s0 - __uint_as_float(h01 << 16);
        float l1 = s1 - __uint_as_float(h01 & 0xffff0000u);
        float l2 = s2 - __uint_as_float(h23 << 16);
        float l3 = s3 - __uint_as_float(h23 & 0xffff0000u);
        uint2 hh = {h01, h23};
        uint2 ll = {pkbf(l0, l1), pkbf(l2, l3)};
        *(uint2*)&sXhi[r][col] = hh;
        *(uint2*)&sXlo[r][col] = ll;
      }
      sq += __shfl_xor(sq, 1);
      sq += __shfl_xor(sq, 2);
      if (q == 0) sX2[r] = -0.5f * sq;
    }

    // issue next tile's global loads; latency hides under stage A+B
    if (it < NITER - 1) {
      const size_t nrow = (size_t)((blockIdx.x + (it + 1) * GRIDN) * 64 + r) * 64;
#pragma unroll
      for (int g = 0; g < 4; ++g)
        v[g] = *(const float4*)(x + nrow + q * 4 + g * 16);
    }
    __syncthreads();  // x tile ready

    // ---- fused stages: per nt-pair, scores -> exp2 -> sPw -> hist MFMAs ----
#pragma unroll
    for (int p = 0; p < 2; ++p) {
#pragma unroll
      for (int u = 0; u < 2; ++u) {
        const int nt = 2 * p + u;
        ushortx8 xh0 = *(const ushortx8*)&sXhi[nt * 16 + l15][quad * 8];
        ushortx8 xh1 = *(const ushortx8*)&sXhi[nt * 16 + l15][32 + quad * 8];
        ushortx8 xl0 = *(const ushortx8*)&sXlo[nt * 16 + l15][quad * 8];
        ushortx8 xl1 = *(const ushortx8*)&sXlo[nt * 16 + l15][32 + quad * 8];
        float4 m2x = *(const float4*)&sX2[nt * 16 + quad * 4];

#pragma unroll
        for (int oo = 0; oo < 2; ++oo) {
          floatx4 acc = {m2x.x + m2c[oo], m2x.y + m2c[oo],
                         m2x.z + m2c[oo], m2x.w + m2c[oo]};
          // log2e*xc = hi*hi + hi*lo + lo*hi (scaled); lo*lo ~1e-5, dropped
          acc = mfma_bf16(xh0, __builtin_bit_cast(ushortx8, chi[oo][0]), acc);
          acc = mfma_bf16(xh1, __builtin_bit_cast(ushortx8, chi[oo][1]), acc);
          acc = mfma_bf16(xh0, __builtin_bit_cast(ushortx8, clo[oo][0]), acc);
          acc = mfma_bf16(xh1, __builtin_bit_cast(ushortx8, clo[oo][1]), acc);
          acc = mfma_bf16(xl0, __builtin_bit_cast(ushortx8, chi[oo][0]), acc);
          acc = mfma_bf16(xl1, __builtin_bit_cast(ushortx8, chi[oo][1]), acc);
          // acc == -log2e*d/2  ->  rbf = exp2(acc)
          unsigned int r01 = pkbf(EXP2F(acc[0]), EXP2F(acc[1]));
          unsigned int r23 = pkbf(EXP2F(acc[2]), EXP2F(acc[3]));
          // C/D layout: o' = l15, n' = quad*4+e  (same-wave buffer, no barrier)
          unsigned short* bp = &sPw[w][oo * 16 + l15][u * 16 + quad * 4];
          *(unsigned int*)(bp)     = r01;
          *(unsigned int*)(bp + 2) = r23;
        }
      }
      // stage B for this pair: A = sPw[o'][n' 0..31], B = xT[i][n], K=32
      ushortx8 a0 = *(const ushortx8*)&sPw[w][l15][quad * 8];
      ushortx8 a1 = *(const ushortx8*)&sPw[w][16 + l15][quad * 8];
#pragma unroll
      for (int itl = 0; itl < 4; ++itl) {
        ushortx8 b = *(const ushortx8*)&sXT[itl * 16 + l15][p * 32 + quad * 8];
        hacc[0][itl] = mfma_bf16(a0, b, hacc[0][itl]);
        hacc[1][itl] = mfma_bf16(a1, b, hacc[1][itl]);
      }
    }
  }

  // ---- epilogue ----
  // D layout: i = itl*16 + l15, o = (2w+oi)*16 + quad*4 + e
  if (use_ws) {
    float* part = ws + (size_t)blockIdx.x * 8192;
#pragma unroll
    for (int oi = 0; oi < 2; ++oi)
#pragma unroll
      for (int itl = 0; itl < 4; ++itl)
#pragma unroll
        for (int e = 0; e < 4; ++e) {
          int o = (2 * w + oi) * 16 + quad * 4 + e;
          int i = itl * 16 + l15;
          part[o * 64 + i] = hacc[oi][itl][e];
        }
  } else {
#pragma unroll
    for (int oi = 0; oi < 2; ++oi)
#pragma unroll
      for (int itl = 0; itl < 4; ++itl)
#pragma unroll
        for (int e = 0; e < 4; ++e) {
          int o = (2 * w + oi) * 16 + quad * 4 + e;
          int i = itl * 16 + l15;
          atomicAdd(out + o * 64 + i, hacc[oi][itl][e]);
        }
  }
}

// sum 1024 per-block partials -> out. 32768 threads, 4 atomics per element.
__global__ void reduce_kernel(const float* __restrict__ ws, float* __restrict__ out) {
  const int tid = blockIdx.x * 256 + threadIdx.x;  // 0..32767
  const int e = tid & 8191;
  const int part = tid >> 13;                      // 0..3
  const float* p = ws + (size_t)part * 256 * 8192 + e;
  float s = 0.f;
#pragma unroll 8
  for (int b = 0; b < 256; ++b) s += p[(size_t)b * 8192];
  atomicAdd(out + e, s);
}

__global__ void zero_out_kernel(float* out, int n) {
  int i = blockIdx.x * 256 + threadIdx.x;
  if (i < n) out[i] = 0.f;
}

extern "C" void kernel_launch(void* const* d_in, const int* in_sizes, int n_in,
                              void* d_out, int out_size, void* d_ws, size_t ws_size,
                              hipStream_t stream) {
  (void)in_sizes; (void)n_in;
  const float* x = (const float*)d_in[0];        // [524288, 64]
  const float* c = (const float*)d_in[1];        // [128, 64]
  float* out = (float*)d_out;                    // [128, 64]
  float* ws  = (float*)d_ws;

  const int use_ws = (ws_size >= (size_t)GRIDN * 8192 * sizeof(float)) ? 1 : 0;

  zero_out_kernel<<<(out_size + 255) / 256, 256, 0, stream>>>(out, out_size);
  rbf_hist_kernel<<<GRIDN, 256, 0, stream>>>(x, c, out, ws, use_ws);
  if (use_ws)
    reduce_kernel<<<128, 256, 0, stream>>>(ws, out);
}

// Round 5
// 212.355 us; speedup vs baseline: 1.0323x; 1.0323x over previous
//
#include <hip/hip_runtime.h>
#include <stdint.h>

// ---------------------------------------------------------------------------
// Fused RBF histogram:  hist[o,i] = sum_n exp(-||x_n - c_o||^2 / 2) * x[n,i]
// N=524288, IN=64, OUT=128.  fp32 in/out.
//
// R5 changes vs R4 (~75us kernel est., flat vs R2):
//  - PREFETCH MOVED: next-tile global loads now issue AFTER the "x tile
//    ready" barrier (top of compute phase). Previously they were issued
//    before it, and the compiler's mandatory `s_waitcnt vmcnt(0)` before
//    `s_barrier` made every iteration stall ~500 cyc waiting for HBM.
//    Now the loads retire under ~2-3K cyc of compute and the next
//    iteration's first barrier drains them when already complete.
//  - stage-A 6-deep dependent MFMA chain split into two parallel chains
//    (depth ~4) + one vector add.
// R4/R3 base: 4 blocks/CU (LDS 37.3 KB), grid 1024, 2 barriers/iter,
// wave-private sPw fusion, sqrt(log2e) pre-scaling so MFMA acc == exp2 arg.
// ---------------------------------------------------------------------------

typedef __bf16 bf16x8 __attribute__((ext_vector_type(8)));
typedef unsigned short ushortx8 __attribute__((ext_vector_type(8)));
typedef float floatx4 __attribute__((ext_vector_type(4)));

#define GRIDN 1024     // 4 blocks/CU x 256 CUs
#define NITER 8        // 8192 tiles / 1024 blocks
#define SCL 1.2011224087864498f   // sqrt(log2(e)); (x*SCL).(c*SCL) = log2e * x.c

#if __has_builtin(__builtin_amdgcn_exp2f)
#define EXP2F(x) __builtin_amdgcn_exp2f(x)
#else
#define EXP2F(x) exp2f(x)
#endif

// round-to-nearest-even fp32 -> bf16 (bit trick; no NaN inputs here)
static __device__ __forceinline__ unsigned int bfbits(float f) {
  unsigned int u = __float_as_uint(f);
  return u + 0x7fffu + ((u >> 16) & 1u);   // rounded value in high 16 bits
}
// pack two fp32 -> bf16x2 (RNE), a in low half
static __device__ __forceinline__ unsigned int pkbf(float a, float b) {
  return (bfbits(a) >> 16) | (bfbits(b) & 0xffff0000u);
}

static __device__ __forceinline__ floatx4 mfma_bf16(ushortx8 a, ushortx8 b, floatx4 c) {
  return __builtin_amdgcn_mfma_f32_16x16x32_bf16(
      __builtin_bit_cast(bf16x8, a), __builtin_bit_cast(bf16x8, b), c, 0, 0, 0);
}

// x-tile LDS row stride 72 shorts = 144 B: 16B-aligned rows, bank step 36%32=4
// -> b128 frag reads are <=2-way conflicted per 16-lane beat (free, m136).
// sPw row stride 40 shorts = 80 B: 16B-aligned, bank step 20 -> 2-way over 16 rows.
#define LSTR 72
#define PSTR 40

__global__ __launch_bounds__(256, 4) void rbf_hist_kernel(
    const float* __restrict__ x, const float* __restrict__ c,
    float* __restrict__ out, float* __restrict__ ws, int use_ws) {
  __shared__ unsigned short sXhi[64][LSTR];   // x*SCL tile, bf16 hi  [n][i]
  __shared__ unsigned short sXlo[64][LSTR];   // x*SCL tile, bf16 lo  [n][i]
  __shared__ unsigned short sXT [64][LSTR];   // x (unscaled) bf16, transposed [i][n]
  __shared__ unsigned short sPw [4][32][PSTR];// per-wave rbf pair-tile [o'][n' 0..31]
  __shared__ float          sX2 [64];         // -0.5 * ||x_n*SCL||^2 (fp32 exact)

  const int t    = threadIdx.x;
  const int lane = t & 63;
  const int w    = t >> 6;      // wave 0..3; owns o-tiles {2w, 2w+1}
  const int l15  = lane & 15;
  const int quad = lane >> 4;

  // ---- one-time: scaled c fragments (hi/lo) for this wave's 2 o-tiles ----
  // B-frag for stage A: B[k=i][col=o]: lane reads c[ot*16+l15][32s+quad*8 ..+7]
  uint4 chi[2][2], clo[2][2];   // packed bf16 pairs, j ascending
  float m2c[2];                 // -0.5 * ||c_o*SCL||^2
#pragma unroll
  for (int oo = 0; oo < 2; ++oo) {
    const int ot = 2 * w + oo;
    float sq = 0.f;
#pragma unroll
    for (int s = 0; s < 2; ++s) {
      const float* p = c + (ot * 16 + l15) * 64 + s * 32 + quad * 8;
      float4 va = *(const float4*)(p);
      float4 vb = *(const float4*)(p + 4);
      float f[8] = {va.x, va.y, va.z, va.w, vb.x, vb.y, vb.z, vb.w};
      unsigned int h[4], l[4];
#pragma unroll
      for (int jp = 0; jp < 4; ++jp) {
        float a = f[2 * jp] * SCL, b = f[2 * jp + 1] * SCL;
        sq = fmaf(a, a, sq);
        sq = fmaf(b, b, sq);
        unsigned int hp = pkbf(a, b);
        float la = a - __uint_as_float(hp << 16);
        float lb = b - __uint_as_float(hp & 0xffff0000u);
        h[jp] = hp;
        l[jp] = pkbf(la, lb);
      }
      chi[oo][s] = uint4{h[0], h[1], h[2], h[3]};
      clo[oo][s] = uint4{l[0], l[1], l[2], l[3]};
    }
    sq += __shfl_xor(sq, 16);
    sq += __shfl_xor(sq, 32);
    m2c[oo] = -0.5f * sq;
  }

  // persistent histogram accumulators: wave w owns o-tiles {2w,2w+1} x 4 i-tiles
  floatx4 hacc[2][4];
#pragma unroll
  for (int a = 0; a < 2; ++a)
#pragma unroll
    for (int b = 0; b < 4; ++b) {
      floatx4 z = {0.f, 0.f, 0.f, 0.f};
      hacc[a][b] = z;
    }

  // register prefetch of first x tile: thread t -> row r=t>>2, cols q*4+g*16
  const int r = t >> 2, q = t & 3;
  float4 v[4];
  {
    const size_t row0 = (size_t)(blockIdx.x * 64 + r) * 64;
#pragma unroll
    for (int g = 0; g < 4; ++g)
      v[g] = *(const float4*)(x + row0 + q * 4 + g * 16);
  }

  for (int it = 0; it < NITER; ++it) {
    __syncthreads();  // prev iteration's reads of sX* done -> safe to overwrite
                      // (also harmlessly drains last iter's prefetch: it
                      //  completed during that iter's ~2-3K cyc of compute)

    // ---- staging: regs -> LDS (scaled hi/lo, unscaled transposed, -x2/2) ----
    {
      float sq = 0.f;
#pragma unroll
      for (int g = 0; g < 4; ++g) {
        const int col = q * 4 + g * 16;
        float f0 = v[g].x, f1 = v[g].y, f2 = v[g].z, f3 = v[g].w;
        // unscaled bf16 for the histogram GEMM (stage B)
        unsigned int u01 = pkbf(f0, f1), u23 = pkbf(f2, f3);
        sXT[col + 0][r] = (unsigned short)(u01 & 0xffffu);
        sXT[col + 1][r] = (unsigned short)(u01 >> 16);
        sXT[col + 2][r] = (unsigned short)(u23 & 0xffffu);
        sXT[col + 3][r] = (unsigned short)(u23 >> 16);
        // scaled hi/lo split for the distance GEMM
        float s0 = f0 * SCL, s1 = f1 * SCL, s2 = f2 * SCL, s3 = f3 * SCL;
        sq = fmaf(s0, s0, sq); sq = fmaf(s1, s1, sq);
        sq = fmaf(s2, s2, sq); sq = fmaf(s3, s3, sq);
        unsigned int h01 = pkbf(s0, s1), h23 = pkbf(s2, s3);
        float l0 = s0 - __uint_as_float(h01 << 16);
        float l1 = s1 - __uint_as_float(h01 & 0xffff0000u);
        float l2 = s2 - __uint_as_float(h23 << 16);
        float l3 = s3 - __uint_as_float(h23 & 0xffff0000u);
        uint2 hh = {h01, h23};
        uint2 ll = {pkbf(l0, l1), pkbf(l2, l3)};
        *(uint2*)&sXhi[r][col] = hh;
        *(uint2*)&sXlo[r][col] = ll;
      }
      sq += __shfl_xor(sq, 1);
      sq += __shfl_xor(sq, 2);
      if (q == 0) sX2[r] = -0.5f * sq;
    }
    __syncthreads();  // x tile ready (drains only LDS writes; no global loads
                      // are outstanding here -> no HBM-latency stall)

    // issue next tile's global loads NOW: they retire during the compute
    // phase below and are drained (already complete) at the next barrier.
    if (it < NITER - 1) {
      const size_t nrow = (size_t)((blockIdx.x + (it + 1) * GRIDN) * 64 + r) * 64;
#pragma unroll
      for (int g = 0; g < 4; ++g)
        v[g] = *(const float4*)(x + nrow + q * 4 + g * 16);
    }

    // ---- fused stages: per nt-pair, scores -> exp2 -> sPw -> hist MFMAs ----
#pragma unroll
    for (int p = 0; p < 2; ++p) {
#pragma unroll
      for (int u = 0; u < 2; ++u) {
        const int nt = 2 * p + u;
        ushortx8 xh0 = *(const ushortx8*)&sXhi[nt * 16 + l15][quad * 8];
        ushortx8 xh1 = *(const ushortx8*)&sXhi[nt * 16 + l15][32 + quad * 8];
        ushortx8 xl0 = *(const ushortx8*)&sXlo[nt * 16 + l15][quad * 8];
        ushortx8 xl1 = *(const ushortx8*)&sXlo[nt * 16 + l15][32 + quad * 8];
        float4 m2x = *(const float4*)&sX2[nt * 16 + quad * 4];

#pragma unroll
        for (int oo = 0; oo < 2; ++oo) {
          // two parallel MFMA chains (depth ~4 instead of 6), then combine
          floatx4 accA = {m2x.x + m2c[oo], m2x.y + m2c[oo],
                          m2x.z + m2c[oo], m2x.w + m2c[oo]};
          floatx4 accB = {0.f, 0.f, 0.f, 0.f};
          accA = mfma_bf16(xh0, __builtin_bit_cast(ushortx8, chi[oo][0]), accA);
          accB = mfma_bf16(xh1, __builtin_bit_cast(ushortx8, clo[oo][1]), accB);
          accA = mfma_bf16(xh1, __builtin_bit_cast(ushortx8, chi[oo][1]), accA);
          accB = mfma_bf16(xl0, __builtin_bit_cast(ushortx8, chi[oo][0]), accB);
          accA = mfma_bf16(xh0, __builtin_bit_cast(ushortx8, clo[oo][0]), accA);
          accB = mfma_bf16(xl1, __builtin_bit_cast(ushortx8, chi[oo][1]), accB);
          floatx4 acc = accA + accB;   // acc == -log2e*d/2 -> rbf = exp2(acc)
          unsigned int r01 = pkbf(EXP2F(acc[0]), EXP2F(acc[1]));
          unsigned int r23 = pkbf(EXP2F(acc[2]), EXP2F(acc[3]));
          // C/D layout: o' = l15, n' = quad*4+e  (same-wave buffer, no barrier)
          unsigned short* bp = &sPw[w][oo * 16 + l15][u * 16 + quad * 4];
          *(unsigned int*)(bp)     = r01;
          *(unsigned int*)(bp + 2) = r23;
        }
      }
      // stage B for this pair: A = sPw[o'][n' 0..31], B = xT[i][n], K=32
      ushortx8 a0 = *(const ushortx8*)&sPw[w][l15][quad * 8];
      ushortx8 a1 = *(const ushortx8*)&sPw[w][16 + l15][quad * 8];
#pragma unroll
      for (int itl = 0; itl < 4; ++itl) {
        ushortx8 b = *(const ushortx8*)&sXT[itl * 16 + l15][p * 32 + quad * 8];
        hacc[0][itl] = mfma_bf16(a0, b, hacc[0][itl]);
        hacc[1][itl] = mfma_bf16(a1, b, hacc[1][itl]);
      }
    }
  }

  // ---- epilogue ----
  // D layout: i = itl*16 + l15, o = (2w+oi)*16 + quad*4 + e
  if (use_ws) {
    float* part = ws + (size_t)blockIdx.x * 8192;
#pragma unroll
    for (int oi = 0; oi < 2; ++oi)
#pragma unroll
      for (int itl = 0; itl < 4; ++itl)
#pragma unroll
        for (int e = 0; e < 4; ++e) {
          int o = (2 * w + oi) * 16 + quad * 4 + e;
          int i = itl * 16 + l15;
          part[o * 64 + i] = hacc[oi][itl][e];
        }
  } else {
#pragma unroll
    for (int oi = 0; oi < 2; ++oi)
#pragma unroll
      for (int itl = 0; itl < 4; ++itl)
#pragma unroll
        for (int e = 0; e < 4; ++e) {
          int o = (2 * w + oi) * 16 + quad * 4 + e;
          int i = itl * 16 + l15;
          atomicAdd(out + o * 64 + i, hacc[oi][itl][e]);
        }
  }
}

// sum 1024 per-block partials -> out. 32768 threads, 4 atomics per element.
__global__ void reduce_kernel(const float* __restrict__ ws, float* __restrict__ out) {
  const int tid = blockIdx.x * 256 + threadIdx.x;  // 0..32767
  const int e = tid & 8191;
  const int part = tid >> 13;                      // 0..3
  const float* p = ws + (size_t)part * 256 * 8192 + e;
  float s = 0.f;
#pragma unroll 8
  for (int b = 0; b < 256; ++b) s += p[(size_t)b * 8192];
  atomicAdd(out + e, s);
}

__global__ void zero_out_kernel(float* out, int n) {
  int i = blockIdx.x * 256 + threadIdx.x;
  if (i < n) out[i] = 0.f;
}

extern "C" void kernel_launch(void* const* d_in, const int* in_sizes, int n_in,
                              void* d_out, int out_size, void* d_ws, size_t ws_size,
                              hipStream_t stream) {
  (void)in_sizes; (void)n_in;
  const float* x = (const float*)d_in[0];        // [524288, 64]
  const float* c = (const float*)d_in[1];        // [128, 64]
  float* out = (float*)d_out;                    // [128, 64]
  float* ws  = (float*)d_ws;

  const int use_ws = (ws_size >= (size_t)GRIDN * 8192 * sizeof(float)) ? 1 : 0;

  zero_out_kernel<<<(out_size + 255) / 256, 256, 0, stream>>>(out, out_size);
  rbf_hist_kernel<<<GRIDN, 256, 0, stream>>>(x, c, out, ws, use_ws);
  if (use_ws)
    reduce_kernel<<<128, 256, 0, stream>>>(ws, out);
}